// Round 6
// baseline (1490.964 us; speedup 1.0000x reference)
//
#include <hip/hip_runtime.h>
#include <cstdint>
#include <cstddef>

#define DEVFN static __device__ __forceinline__

typedef __attribute__((ext_vector_type(8))) short short8;
typedef __attribute__((ext_vector_type(4))) float f32x4;

constexpr int NN  = 8000;   // nodes
constexpr int NE  = 32000;  // edges (without self loops)
constexpr int ET  = NE + NN;// with self loops
constexpr int NG  = 256;    // graphs
constexpr int F   = 680;
constexpr int NH  = 10;
constexpr int HF  = 6800;

constexpr int MP   = 8192;   // node rows padded (64 M-tiles of 128)
constexpr int KP1  = 704;    // F padded to 64
constexpr int NP   = 6912;   // HF padded to 256 (27*256)
constexpr int KP2  = 6848;   // HF padded to 64 (107*64)
constexpr int KM1P = 13632;  // 2*HF padded to 64 (213*64)

DEVFN unsigned short f2bf(float f) {
  unsigned u = __float_as_uint(f);
  u += 0x7fffu + ((u >> 16) & 1u);
  return (unsigned short)(u >> 16);
}
DEVFN float bf2f(unsigned short b) { return __uint_as_float(((unsigned)b) << 16); }

// Packing: within each 64-element K block of row r, logical element k stored at
// perm64(k,r): 16B chunk index XORed with (r&7). With the 16-row fragment read
// pattern (rows lane&15, chunk (4ks|g4)^(lane&7)) this measured 0 LDS bank
// conflicts in rounds 1-4 (the round-5 32-row variant measured 7.1e7 — reverted).
// Applied identically to all GEMM A and B^T operands -> MFMA k-order consistent.
DEVFN int perm64(int k, int r) {
  return (((k >> 3) ^ (r & 7)) << 3) | (k & 7);
}

DEVFN void gload16(const void* g, void* l) {
  __builtin_amdgcn_global_load_lds(
      (const __attribute__((address_space(1))) unsigned int*)g,
      (__attribute__((address_space(3))) unsigned int*)l, 16, 0, 0);
}

DEVFN f32x4 mfma16(short8 a, short8 b, f32x4 c) {
  asm("v_mfma_f32_16x16x32_bf16 %0, %1, %2, %0" : "+v"(c) : "v"(a), "v"(b));
  return c;
}

// ---- 128x256 GEMM, 8 waves (2M x 4N, 64x64/wave), BK=64, 16x16x32 MFMA ----
// C[M][N] = A[M][K] * BT[N][K]^T.  A,BT bf16 perm64-packed, row stride K (K%64==0).
// LDS: 2 slots x (A 16KB [128 rows][128B] + B 32KB [256 rows][128B]) = 96KB.
// Per tile: ph0 issues 12 reads (A-mh0, B-nh0, B-nh1) then Q00; ph1 issues A-mh1
// then Q01; barrier (all B reads consumed) -> stage B(t+2); Q11; barrier (A reads
// consumed) -> stage A(t+2); Q10 (register-only) covers counted vmcnt(6).
// OUT_MODE: 0=f32 plain(+bias), 1=bf16 plain, 2=bf16 perm64, 3=f32 split-K slice
template<int OUT_MODE, bool BIAS, bool RELU, bool SWZ>
__global__ __launch_bounds__(512, 2) void gemm256(
    const unsigned short* __restrict__ A, const unsigned short* __restrict__ BT,
    void* __restrict__ C, const float* __restrict__ bias,
    int K, int cstride, int nvalid, int Mt, int KC) {
  __shared__ alignas(16) char Lds[98304];
  const int tid = threadIdx.x;
  const int wave = tid >> 6, lane = tid & 63;
  const int wm = wave >> 2, wn = wave & 3;          // 2x4 wave grid
  const int g4 = lane >> 4, l15 = lane & 15, l7 = lane & 7;

  int bm, bn;
  if (SWZ) {
    // one bn per XCD per round (B panel 3.5MB -> L2); all bm sweep A per round
    const int xcd = blockIdx.x & 7;
    const int j = blockIdx.x >> 3;
    bm = j & 63;
    bn = (j >> 6) * 8 + xcd;
    const int Nt = (nvalid + 255) >> 8;
    if (bn >= Nt) return;                           // dead pad block
  } else {
    bm = blockIdx.x % Mt;
    bn = blockIdx.x / Mt;
  }

  const int NTt = K >> 6;
  const int kb = blockIdx.z * KC;
  const int NT = min(KC, NTt - kb);
  const unsigned short* Ag = A + (size_t)bm * 128 * K + (size_t)kb * 64;
  const unsigned short* Bg = BT + (size_t)bn * 256 * K + (size_t)kb * 64;

  // staging: thread handles 16B chunk q = r*512 + tid; row = q>>3, chunk = q&7
  const size_t soff = (size_t)(tid >> 3) * K + (size_t)(tid & 7) * 8;

  auto stageA = [&](int t) {   // 2 gloads: rows 0..127
    char* base = Lds + (t & 1) * 49152 + (wave << 10);
    const unsigned short* src = Ag + soff + (size_t)t * 64;
    gload16(src, base);
    gload16(src + (size_t)64 * K, base + 8192);
  };
  auto stageB = [&](int t) {   // 4 gloads: rows 0..255
    char* base = Lds + (t & 1) * 49152 + 16384 + (wave << 10);
    const unsigned short* src = Bg + soff + (size_t)t * 64;
    gload16(src, base);
    gload16(src + (size_t)64 * K, base + 8192);
    gload16(src + (size_t)128 * K, base + 16384);
    gload16(src + (size_t)192 * K, base + 24576);
  };

  f32x4 acc[4][4];
#pragma unroll
  for (int i = 0; i < 4; i++)
#pragma unroll
    for (int j = 0; j < 4; j++) acc[i][j] = (f32x4){0.f, 0.f, 0.f, 0.f};

  short8 aR[2][2][2], bR[2][2][2];   // [half][frag][ks]

#define RD_A(MH, AB) do {                                                        \
  _Pragma("unroll") for (int i2 = 0; i2 < 2; ++i2)                               \
  _Pragma("unroll") for (int ks = 0; ks < 2; ++ks)                               \
    aR[MH][i2][ks] = *(const short8*)((AB) + (wm * 64 + ((MH) * 2 + i2) * 16 + l15) * 128 \
                                      + ((((ks << 2) | g4) ^ l7) << 4));          \
} while (0)

#define RD_B(NH, BB) do {                                                        \
  _Pragma("unroll") for (int j2 = 0; j2 < 2; ++j2)                               \
  _Pragma("unroll") for (int ks = 0; ks < 2; ++ks)                               \
    bR[NH][j2][ks] = *(const short8*)((BB) + (wn * 64 + ((NH) * 2 + j2) * 16 + l15) * 128 \
                                      + ((((ks << 2) | g4) ^ l7) << 4));          \
} while (0)

#define MM(MH, NH) do {                                                          \
  __builtin_amdgcn_s_setprio(1);                                                 \
  _Pragma("unroll") for (int i2 = 0; i2 < 2; ++i2)                               \
  _Pragma("unroll") for (int j2 = 0; j2 < 2; ++j2)                               \
  _Pragma("unroll") for (int ks = 0; ks < 2; ++ks)                               \
    acc[(MH) * 2 + i2][(NH) * 2 + j2] =                                          \
        mfma16(aR[MH][i2][ks], bR[NH][j2][ks], acc[(MH) * 2 + i2][(NH) * 2 + j2]); \
  __builtin_amdgcn_s_setprio(0);                                                 \
} while (0)

  // prologue: stage tiles 0 and 1; wait tile 0 only (tile 1 stays in flight)
  stageA(0); stageB(0);
  if (NT > 1) {
    stageA(1); stageB(1);
    asm volatile("s_waitcnt vmcnt(6)" ::: "memory");
  } else {
    asm volatile("s_waitcnt vmcnt(0)" ::: "memory");
  }
  asm volatile("s_barrier" ::: "memory");

  for (int t = 0; t < NT; ++t) {
    const char* Ab = Lds + (t & 1) * 49152;
    const char* Bb = Ab + 16384;
    const bool pf = (t + 2 < NT);

    // ph0: issue A-mh0 + both B halves (12 b128), compute Q00
    RD_A(0, Ab);
    RD_B(0, Bb);
    RD_B(1, Bb);
    MM(0, 0);
    // ph1: issue A-mh1, compute Q01 (bR[1] arrived under Q00)
    RD_A(1, Ab);
    MM(0, 1);
    asm volatile("s_barrier" ::: "memory");   // all waves consumed their B reads
    if (pf) stageB(t + 2);
    // ph2: Q11 (aR[1] arrived under Q01)
    MM(1, 1);
    asm volatile("s_barrier" ::: "memory");   // all waves consumed their A reads
    if (pf) stageA(t + 2);
    // ph3: register-only Q10 covers the counted vmcnt for tile t+1
    MM(1, 0);
    if (pf) asm volatile("s_waitcnt vmcnt(6)" ::: "memory");
    else    asm volatile("s_waitcnt vmcnt(0)" ::: "memory");
    asm volatile("s_barrier" ::: "memory");   // tile t+1 resident for all waves
  }

#undef RD_A
#undef RD_B
#undef MM

  // epilogue: 16x16 C/D layout col = lane&15, row = (lane>>4)*4 + tt  [m89/m91]
  const int m0 = bm * 128 + wm * 64;
  const int n0 = bn * 256 + wn * 64;
  const int rb = g4 * 4;
#pragma unroll
  for (int i = 0; i < 4; i++) {
#pragma unroll
    for (int j = 0; j < 4; j++) {
      int c = n0 + j * 16 + l15;
      if (c >= nvalid) continue;
      float bv = BIAS ? bias[c] : 0.f;
#pragma unroll
      for (int tt = 0; tt < 4; tt++) {
        int r = m0 + i * 16 + rb + tt;
        float v = acc[i][j][tt] + bv;
        if (RELU) v = fmaxf(v, 0.f);
        if (OUT_MODE == 0) {
          ((float*)C)[(size_t)r * cstride + c] = v;
        } else if (OUT_MODE == 1) {
          ((unsigned short*)C)[(size_t)r * cstride + c] = f2bf(v);
        } else if (OUT_MODE == 2) {
          int pos = (c & ~63) + perm64(c & 63, r);
          ((unsigned short*)C)[(size_t)r * cstride + pos] = f2bf(v);
        } else {
          ((float*)C)[(size_t)blockIdx.z * (Mt * 128) * cstride + (size_t)r * cstride + c] = v;
        }
      }
    }
  }
}

// ---------------- split-K finish: sum slices + bias (+relu) -> bf16 perm64 ----------
template<bool RELU>
__global__ void finish_kernel(const float* __restrict__ acc, const float* __restrict__ bias,
                              unsigned short* __restrict__ out, int S, int M, int N) {
  int idx = blockIdx.x * 256 + threadIdx.x;
  if (idx >= M * N) return;
  int r = idx / N, c = idx - r * N;
  float s = bias[c];
  for (int k = 0; k < S; k++) s += acc[(size_t)k * M * N + (size_t)r * N + c];
  if (RELU) s = fmaxf(s, 0.f);
  out[(size_t)r * N + (c & ~63) + perm64(c & 63, r)] = f2bf(s);
}

// ---------------- conversions ----------------
__global__ void conv_x_kernel(const float* __restrict__ x, unsigned short* __restrict__ out) {
  int idx = blockIdx.x * 256 + threadIdx.x;          // one per 4-elem group
  constexpr int GR = KP1 / 4;
  if (idx >= MP * GR) return;
  int row = idx / GR, k = (idx - row * GR) * 4;
  unsigned short v[4] = {0, 0, 0, 0};
  if (row < NN && k < F) {
    const float* p = x + (size_t)row * F + k;
    v[0] = f2bf(p[0]); v[1] = f2bf(p[1]); v[2] = f2bf(p[2]); v[3] = f2bf(p[3]);
  }
  int pos = (k & ~63) + perm64(k & 63, row);
  uint2 pk;
  pk.x = (unsigned)v[0] | ((unsigned)v[1] << 16);
  pk.y = (unsigned)v[2] | ((unsigned)v[3] << 16);
  *(uint2*)&out[(size_t)row * KP1 + pos] = pk;
}

// in: f32 [K][N] row-major  ->  out: bf16 [NPad][KPad] (transposed, perm64)
__global__ void convT_kernel(const float* __restrict__ in, unsigned short* __restrict__ out,
                             int K, int N, int KPad, int NPad) {
  __shared__ float tile[32][33];
  int n0 = blockIdx.x * 32, k0 = blockIdx.y * 32;
  int tx = threadIdx.x, ty = threadIdx.y;
#pragma unroll
  for (int i = 0; i < 4; i++) {
    int k = k0 + ty + i * 8, n = n0 + tx;
    tile[ty + i * 8][tx] = (k < K && n < N) ? in[(size_t)k * N + n] : 0.f;
  }
  __syncthreads();
#pragma unroll
  for (int i = 0; i < 4; i++) {
    int n = n0 + ty + i * 8, k = k0 + tx;
    if (n < NPad && k < KPad) {
      int pos = (k & ~63) + perm64(k & 63, n);
      out[(size_t)n * KPad + pos] = f2bf(tile[tx][ty + i * 8]);
    }
  }
}

// ---------------- attention logits ----------------
__global__ void logits_kernel(const unsigned short* __restrict__ xh,
                              const float* __restrict__ a_src, const float* __restrict__ a_dst,
                              float* __restrict__ al_s, float* __restrict__ al_d) {
  int wid = blockIdx.x * 4 + (threadIdx.x >> 6);
  int lane = threadIdx.x & 63;
  int n = wid / NH, h = wid - n * NH;
  if (n >= NN) return;
  const unsigned short* row = xh + (size_t)n * NP + h * F;
  const float* as = a_src + h * F;
  const float* ad = a_dst + h * F;
  float ss = 0.f, sd = 0.f;
  for (int f0 = lane; f0 < F; f0 += 64) {
    float v = bf2f(row[f0]);
    ss += v * as[f0]; sd += v * ad[f0];
  }
#pragma unroll
  for (int o = 32; o > 0; o >>= 1) { ss += __shfl_down(ss, o); sd += __shfl_down(sd, o); }
  if (lane == 0) { al_s[wid] = ss; al_d[wid] = sd; }
}

// ---------------- CSR over dst ----------------
__global__ void edge_count_kernel(const int* __restrict__ ei, int* __restrict__ deg) {
  int e = blockIdx.x * 256 + threadIdx.x;
  if (e >= ET) return;
  int d = (e < NE) ? ei[NE + e] : (e - NE);
  atomicAdd(&deg[d], 1);
}

__global__ void scan_kernel(const int* __restrict__ deg, int* __restrict__ rs,
                            int* __restrict__ cursor) {
  __shared__ int part[1024];
  int t = threadIdx.x;
  int base = t * 8, s = 0, loc[8];
#pragma unroll
  for (int i = 0; i < 8; i++) { loc[i] = s; int idx = base + i; s += (idx < NN) ? deg[idx] : 0; }
  part[t] = s;
  __syncthreads();
  for (int off = 1; off < 1024; off <<= 1) {
    int v = (t >= off) ? part[t - off] : 0;
    __syncthreads();
    part[t] += v;
    __syncthreads();
  }
  int pre = (t > 0) ? part[t - 1] : 0;
#pragma unroll
  for (int i = 0; i < 8; i++) {
    int idx = base + i;
    if (idx <= NN) { rs[idx] = pre + loc[i]; cursor[idx] = pre + loc[i]; }
  }
}

__global__ void edge_fill_kernel(const int* __restrict__ ei, int* __restrict__ cursor,
                                 int* __restrict__ eidx) {
  int e = blockIdx.x * 256 + threadIdx.x;
  if (e >= ET) return;
  int d = (e < NE) ? ei[NE + e] : (e - NE);
  int pos = atomicAdd(&cursor[d], 1);
  eidx[pos] = e;
}

__global__ void dinv_kernel(const int* __restrict__ deg, float* __restrict__ dinv) {
  int n = blockIdx.x * 256 + threadIdx.x;
  if (n < NN) dinv[n] = rsqrtf((float)max(deg[n], 1));
}

// ---------------- edge softmax ----------------
__global__ void alpha_kernel(const int* __restrict__ ei, const int* __restrict__ rs,
                             const int* __restrict__ eidx, const float* __restrict__ al_s,
                             const float* __restrict__ al_d, float* __restrict__ alpha) {
  int w = blockIdx.x * 256 + threadIdx.x;
  if (w >= NN * NH) return;
  int n = w / NH, h = w - n * NH;
  int s0 = rs[n], s1 = rs[n + 1];
  float ad = al_d[w];
  float m = -3.0e38f;
  for (int i = s0; i < s1; i++) {
    int e = eidx[i]; int s = (e < NE) ? ei[e] : (e - NE);
    float x = al_s[s * NH + h] + ad;
    x = (x > 0.f) ? x : 0.2f * x;
    m = fmaxf(m, x);
  }
  float z = 0.f;
  for (int i = s0; i < s1; i++) {
    int e = eidx[i]; int s = (e < NE) ? ei[e] : (e - NE);
    float x = al_s[s * NH + h] + ad;
    x = (x > 0.f) ? x : 0.2f * x;
    float ex = __expf(x - m);
    alpha[(size_t)i * NH + h] = ex;
    z += ex;
  }
  float inv = 1.f / (z + 1e-16f);
  for (int i = s0; i < s1; i++) alpha[(size_t)i * NH + h] *= inv;
}

DEVFN void axpy8(float al, uint4 r, float* a) {
  a[0] += al * bf2f((unsigned short)(r.x & 0xffff));
  a[1] += al * bf2f((unsigned short)(r.x >> 16));
  a[2] += al * bf2f((unsigned short)(r.y & 0xffff));
  a[3] += al * bf2f((unsigned short)(r.y >> 16));
  a[4] += al * bf2f((unsigned short)(r.z & 0xffff));
  a[5] += al * bf2f((unsigned short)(r.z >> 16));
  a[6] += al * bf2f((unsigned short)(r.w & 0xffff));
  a[7] += al * bf2f((unsigned short)(r.w >> 16));
}
DEVFN uint4 pack8(const float* a) {
  uint4 p;
  p.x = (unsigned)f2bf(a[0]) | ((unsigned)f2bf(a[1]) << 16);
  p.y = (unsigned)f2bf(a[2]) | ((unsigned)f2bf(a[3]) << 16);
  p.z = (unsigned)f2bf(a[4]) | ((unsigned)f2bf(a[5]) << 16);
  p.w = (unsigned)f2bf(a[6]) | ((unsigned)f2bf(a[7]) << 16);
  return p;
}

constexpr int MAXE = 256;   // per-block cached edges (deg mean ~5; overflow path below)

// ---------------- GAT aggregation -> h (bf16, perm64 layout) ----------------
__global__ __launch_bounds__(256) void gat_agg_kernel(
    const unsigned short* __restrict__ xh, const int* __restrict__ ei,
    const int* __restrict__ rs, const int* __restrict__ eidx,
    const float* __restrict__ alpha, const float* __restrict__ bgat,
    unsigned short* __restrict__ hbf) {
  __shared__ int   Ls[MAXE];
  __shared__ float La[MAXE][NH];
  int n = blockIdx.x, t = threadIdx.x;
  int s0 = rs[n], d = rs[n + 1] - s0;
  int dc = min(d, MAXE);
  for (int i = t; i < dc; i += 256) {
    int e = eidx[s0 + i]; Ls[i] = (e < NE) ? ei[e] : (e - NE);
  }
  for (int j = t; j < dc * NH; j += 256)
    La[j / NH][j % NH] = alpha[(size_t)(s0 + j / NH) * NH + j % NH];
  __syncthreads();
  for (int c8 = t; c8 < KP2 / 8; c8 += 256) {
    int c = c8 * 8;
    int pos = (c & ~63) + ((((c >> 3) & 7) ^ (n & 7)) << 3);  // perm64, 8 contiguous
    if (c >= HF) {
      *(uint4*)&hbf[(size_t)n * KP2 + pos] = make_uint4(0u, 0u, 0u, 0u);
      continue;
    }
    int h = c / F;                          // 680 % 8 == 0: chunk never straddles heads
    float a[8] = {0.f, 0.f, 0.f, 0.f, 0.f, 0.f, 0.f, 0.f};
    for (int i = 0; i < dc; ++i)
      axpy8(La[i][h], *(const uint4*)&xh[(size_t)Ls[i] * NP + c], a);
    for (int i = MAXE; i < d; ++i) {        // overflow path (unused for this graph)
      int e = eidx[s0 + i]; int s = (e < NE) ? ei[e] : (e - NE);
      axpy8(alpha[(size_t)(s0 + i) * NH + h], *(const uint4*)&xh[(size_t)s * NP + c], a);
    }
#pragma unroll
    for (int q = 0; q < 8; ++q) a[q] = fmaxf(a[q] + bgat[c + q], 0.f);
    *(uint4*)&hbf[(size_t)n * KP2 + pos] = pack8(a);
  }
}

// ---------------- GCN aggregation -> h2 (bf16, plain layout) ----------------
__global__ __launch_bounds__(256) void gcn_agg_kernel(
    const unsigned short* __restrict__ xw, const int* __restrict__ ei,
    const int* __restrict__ rs, const int* __restrict__ eidx,
    const float* __restrict__ dinv, const float* __restrict__ bgcn,
    unsigned short* __restrict__ h2) {
  __shared__ int   Ls[MAXE];
  __shared__ float Lw[MAXE];
  int n = blockIdx.x, t = threadIdx.x;
  int s0 = rs[n], d = rs[n + 1] - s0;
  int dc = min(d, MAXE);
  float dn = dinv[n];
  for (int i = t; i < dc; i += 256) {
    int e = eidx[s0 + i]; int s = (e < NE) ? ei[e] : (e - NE);
    Ls[i] = s; Lw[i] = dinv[s] * dn;
  }
  __syncthreads();
  for (int c8 = t; c8 < HF / 8; c8 += 256) {
    int c = c8 * 8;
    float a[8] = {0.f, 0.f, 0.f, 0.f, 0.f, 0.f, 0.f, 0.f};
    for (int i = 0; i < dc; ++i)
      axpy8(Lw[i], *(const uint4*)&xw[(size_t)Ls[i] * NP + c], a);
    for (int i = MAXE; i < d; ++i) {
      int e = eidx[s0 + i]; int s = (e < NE) ? ei[e] : (e - NE);
      axpy8(dinv[s] * dn, *(const uint4*)&xw[(size_t)s * NP + c], a);
    }
#pragma unroll
    for (int q = 0; q < 8; ++q) a[q] = fmaxf(a[q] + bgcn[c + q], 0.f);
    *(uint4*)&h2[(size_t)n * KP2 + c] = pack8(a);
  }
}

// ---------------- pooling ----------------
__global__ void pool_init_kernel(int* gstart, int* gend, int* gcnt) {
  int g = threadIdx.x;
  gstart[g] = 0x7fffffff; gend[g] = 0; gcnt[g] = 0;
}
__global__ void pool_scan_kernel(const int* __restrict__ batch, int* gstart, int* gend, int* gcnt) {
  int n = blockIdx.x * 256 + threadIdx.x;
  if (n >= NN) return;
  int b = batch[n];
  if (b >= 0 && b < NG) {
    atomicMin(&gstart[b], n);
    atomicMax(&gend[b], n + 1);
    atomicAdd(&gcnt[b], 1);
  }
}
// batch is contiguous (arange // (N/G)) -> [gstart,gend) all belong to g
__global__ void pool_kernel(const unsigned short* __restrict__ h2,
                            const int* __restrict__ gstart, const int* __restrict__ gend,
                            const int* __restrict__ gcnt, unsigned short* __restrict__ gbf) {
  int g = blockIdx.x, t = threadIdx.x;
  int s = gstart[g], e = gend[g];
  float inv = 1.f / (float)max(gcnt[g], 1);
  for (int c8 = t; c8 < HF / 8; c8 += 256) {
    int c = c8 * 8;
    float mx[8], sm[8];
#pragma unroll
    for (int q = 0; q < 8; ++q) { mx[q] = -3.0e38f; sm[q] = 0.f; }
    for (int n = s; n < e; ++n) {
      uint4 r = *(const uint4*)&h2[(size_t)n * KP2 + c];
      float v[8];
      v[0] = bf2f((unsigned short)(r.x & 0xffff)); v[1] = bf2f((unsigned short)(r.x >> 16));
      v[2] = bf2f((unsigned short)(r.y & 0xffff)); v[3] = bf2f((unsigned short)(r.y >> 16));
      v[4] = bf2f((unsigned short)(r.z & 0xffff)); v[5] = bf2f((unsigned short)(r.z >> 16));
      v[6] = bf2f((unsigned short)(r.w & 0xffff)); v[7] = bf2f((unsigned short)(r.w >> 16));
#pragma unroll
      for (int q = 0; q < 8; ++q) { mx[q] = fmaxf(mx[q], v[q]); sm[q] += v[q]; }
    }
#pragma unroll
    for (int q = 0; q < 8; ++q) sm[q] *= inv;
    int c2 = HF + c;
    int pos1 = (c & ~63) + ((((c >> 3) & 7) ^ (g & 7)) << 3);
    int pos2 = (c2 & ~63) + ((((c2 >> 3) & 7) ^ (g & 7)) << 3);
    *(uint4*)&gbf[(size_t)g * KM1P + pos1] = pack8(mx);
    *(uint4*)&gbf[(size_t)g * KM1P + pos2] = pack8(sm);
  }
}

// ---------------- launch ----------------
extern "C" void kernel_launch(void* const* d_in, const int* in_sizes, int n_in,
                              void* d_out, int out_size, void* d_ws, size_t ws_size,
                              hipStream_t stream) {
  (void)in_sizes; (void)n_in; (void)out_size; (void)ws_size;
  const float* x     = (const float*)d_in[0];
  const int*   ei    = (const int*)d_in[1];
  const int*   batch = (const int*)d_in[2];
  const float* W_gat = (const float*)d_in[3];
  const float* a_src = (const float*)d_in[4];
  const float* a_dst = (const float*)d_in[5];
  const float* b_gat = (const float*)d_in[6];
  const float* W_gcn = (const float*)d_in[7];
  const float* b_gcn = (const float*)d_in[8];
  const float* W1    = (const float*)d_in[9];
  const float* b1    = (const float*)d_in[10];
  const float* W2    = (const float*)d_in[11];
  const float* b2    = (const float*)d_in[12];
  const float* W3    = (const float*)d_in[13];
  const float* b3    = (const float*)d_in[14];
  float* out = (float*)d_out;

  char* ws = (char*)d_ws;
  size_t off = 0;
  auto alloc = [&](size_t bytes) -> void* {
    void* p = ws + off;
    off += (bytes + 255) & ~(size_t)255;
    return p;
  };
  unsigned short* bufA  = (unsigned short*)alloc((size_t)MP * NP * 2);   // xh, then xw
  unsigned short* bufB  = (unsigned short*)alloc((size_t)MP * KP2 * 2);  // h (perm), then h2 (plain)
  unsigned short* wgcnT = (unsigned short*)alloc((size_t)NP * KP2 * 2);
  unsigned short* xbf   = (unsigned short*)alloc((size_t)MP * KP1 * 2);
  unsigned short* wgatT = (unsigned short*)alloc((size_t)NP * KP1 * 2);
  unsigned short* w1T   = (unsigned short*)alloc((size_t)512 * KM1P * 2);
  unsigned short* gbf   = (unsigned short*)alloc((size_t)NG * KM1P * 2);
  unsigned short* w2T   = (unsigned short*)alloc((size_t)256 * 512 * 2);
  unsigned short* w3T   = (unsigned short*)alloc((size_t)256 * 128 * 2);
  unsigned short* g1bf  = (unsigned short*)alloc((size_t)NG * 512 * 2);
  unsigned short* g2bf  = (unsigned short*)alloc((size_t)NG * 128 * 2);
  float* accf  = (float*)alloc((size_t)32 * 256 * 512 * 4);              // split-K slices
  float* al_s  = (float*)alloc((size_t)NN * NH * 4);
  float* al_d  = (float*)alloc((size_t)NN * NH * 4);
  float* alpha = (float*)alloc((size_t)ET * NH * 4);
  float* dinv  = (float*)alloc((size_t)NN * 4);
  int* deg    = (int*)alloc((size_t)NN * 4);
  int* rs     = (int*)alloc((size_t)(NN + 1) * 4);
  int* cursor = (int*)alloc((size_t)(NN + 1) * 4);
  int* eidx   = (int*)alloc((size_t)ET * 4);
  int* gstart = (int*)alloc((size_t)NG * 4);
  int* gend   = (int*)alloc((size_t)NG * 4);
  int* gcnt   = (int*)alloc((size_t)NG * 4);

  constexpr int GRID_SWZ = 8 * 64 * 4;   // xcd(8) x bm(64) x bn-rounds(4) = 2048

  // --- stage 0: conversions / padding ---
  conv_x_kernel<<<(MP * (KP1 / 4)) / 256, 256, 0, stream>>>(x, xbf);
  convT_kernel<<<dim3(NP / 32, KP1 / 32), dim3(32, 8), 0, stream>>>(W_gat, wgatT, F, HF, KP1, NP);
  convT_kernel<<<dim3(NP / 32, KP2 / 32), dim3(32, 8), 0, stream>>>(W_gcn, wgcnT, HF, HF, KP2, NP);
  convT_kernel<<<dim3(512 / 32, KM1P / 32), dim3(32, 8), 0, stream>>>(W1, w1T, 2 * HF, 512, KM1P, 512);
  convT_kernel<<<dim3(256 / 32, 512 / 32), dim3(32, 8), 0, stream>>>(W2, w2T, 512, 128, 512, 256);
  convT_kernel<<<dim3(256 / 32, 128 / 32), dim3(32, 8), 0, stream>>>(W3, w3T, 128, 64, 128, 256);
  hipMemsetAsync(deg, 0, (size_t)NN * 4, stream);
  hipMemsetAsync((char*)bufB + (size_t)NN * KP2 * 2, 0, (size_t)(MP - NN) * KP2 * 2, stream);
  hipMemsetAsync(gbf, 0, (size_t)NG * KM1P * 2, stream);   // K-pad cols of pooled features

  // --- GEMM1: xh = x @ W_gat (bf16 out, plain layout) ---
  gemm256<1, false, false, true><<<dim3(GRID_SWZ, 1, 1), 512, 0, stream>>>(
      xbf, wgatT, bufA, nullptr, KP1, NP, NP, 64, KP1 / 64);

  // --- attention logits ---
  logits_kernel<<<(NN * NH) / 4, 256, 0, stream>>>(bufA, a_src, a_dst, al_s, al_d);

  // --- CSR build over dst ---
  edge_count_kernel<<<(ET + 255) / 256, 256, 0, stream>>>(ei, deg);
  scan_kernel<<<1, 1024, 0, stream>>>(deg, rs, cursor);
  edge_fill_kernel<<<(ET + 255) / 256, 256, 0, stream>>>(ei, cursor, eidx);
  dinv_kernel<<<(NN + 255) / 256, 256, 0, stream>>>(deg, dinv);

  // --- edge softmax ---
  alpha_kernel<<<(NN * NH + 255) / 256, 256, 0, stream>>>(ei, rs, eidx, al_s, al_d, alpha);

  // --- GAT aggregate -> h (bf16, perm64 layout) ---
  gat_agg_kernel<<<NN, 256, 0, stream>>>(bufA, ei, rs, eidx, alpha, b_gat, bufB);

  // --- GCN GEMM: xw = h @ W_gcn ---
  gemm256<1, false, false, true><<<dim3(GRID_SWZ, 1, 1), 512, 0, stream>>>(
      bufB, wgcnT, bufA, nullptr, KP2, NP, NP, 64, KP2 / 64);

  // --- GCN aggregate -> h2 (bf16, plain layout, reuses bufB) ---
  gcn_agg_kernel<<<NN, 256, 0, stream>>>(bufA, ei, rs, eidx, dinv, b_gcn, bufB);

  // --- pooling -> g (bf16, perm64 layout) ---
  pool_init_kernel<<<1, 256, 0, stream>>>(gstart, gend, gcnt);
  pool_scan_kernel<<<(NN + 255) / 256, 256, 0, stream>>>(batch, gstart, gend, gcnt);
  pool_kernel<<<NG, 256, 0, stream>>>(bufB, gstart, gend, gcnt, gbf);

  // --- MLP (split-K, f32 slices, then finish) ---
  // MLP1: 256x512 @ K=13632 (213 tiles): z=31 slices x KC=7 -> 124 blocks
  gemm256<3, false, false, false><<<dim3(2 * 2, 1, 31), 512, 0, stream>>>(
      gbf, w1T, accf, nullptr, KM1P, 512, 512, 2, 7);
  finish_kernel<true><<<(256 * 512) / 256, 256, 0, stream>>>(accf, b1, g1bf, 31, 256, 512);

  // MLP2: 256x128 @ K=512 (8 tiles): z=4 x KC=2 -> 8 blocks
  gemm256<3, false, false, false><<<dim3(2, 1, 4), 512, 0, stream>>>(
      g1bf, w2T, accf, nullptr, 512, 128, 128, 2, 2);
  finish_kernel<false><<<(256 * 128) / 256, 256, 0, stream>>>(accf, b2, g2bf, 4, 256, 128);

  // MLP3: 256x64 @ K=128 (2 tiles): direct f32 out with bias
  gemm256<0, true, false, false><<<dim3(2, 1, 1), 512, 0, stream>>>(
      g2bf, w3T, out, b3, 128, 64, 64, 2, 2);
}

// Round 7
// 1366.225 us; speedup vs baseline: 1.0913x; 1.0913x over previous
//
#include <hip/hip_runtime.h>
#include <cstdint>
#include <cstddef>

#define DEVFN static __device__ __forceinline__

typedef __attribute__((ext_vector_type(8))) short short8;
typedef __attribute__((ext_vector_type(4))) float f32x4;

constexpr int NN  = 8000;   // nodes
constexpr int NE  = 32000;  // edges (without self loops)
constexpr int ET  = NE + NN;// with self loops
constexpr int NG  = 256;    // graphs
constexpr int F   = 680;
constexpr int NH  = 10;
constexpr int HF  = 6800;

constexpr int MP   = 8192;   // node rows padded (32 M-tiles of 256)
constexpr int KP1  = 704;    // F padded to 64
constexpr int NP   = 6912;   // HF padded to 256 (27*256)
constexpr int KP2  = 6848;   // HF padded to 64 (107*64)
constexpr int KM1P = 13632;  // 2*HF padded to 64 (213*64)

DEVFN unsigned short f2bf(float f) {
  unsigned u = __float_as_uint(f);
  u += 0x7fffu + ((u >> 16) & 1u);
  return (unsigned short)(u >> 16);
}
DEVFN float bf2f(unsigned short b) { return __uint_as_float(((unsigned)b) << 16); }

// Packing: within each 64-element K block of row r, logical element k stored at
// perm64(k,r): 16B chunk index XORed with (r&7). With the 16-row fragment read
// pattern (rows lane&15, chunk (4ks|g4)^(lane&7)) this measured 0 LDS bank
// conflicts (rounds 1-4; round-5's 32-row variant hit 7.1e7 and was reverted).
// Applied identically to all GEMM A and B^T operands -> MFMA k-order consistent.
DEVFN int perm64(int k, int r) {
  return (((k >> 3) ^ (r & 7)) << 3) | (k & 7);
}

DEVFN void gload16(const void* g, void* l) {
  __builtin_amdgcn_global_load_lds(
      (const __attribute__((address_space(1))) unsigned int*)g,
      (__attribute__((address_space(3))) unsigned int*)l, 16, 0, 0);
}

DEVFN f32x4 mfma16(short8 a, short8 b, f32x4 c) {
  asm("v_mfma_f32_16x16x32_bf16 %0, %1, %2, %0" : "+v"(c) : "v"(a), "v"(b));
  return c;
}

// ---- 256x256 GEMM, 8 waves (2Mx4N, 128x64/wave), BK=64, rotated pipeline ----
// C[M][N] = A[M][K] * BT[N][K]^T.  A,BT bf16 perm64-packed, row stride K (K%64==0).
// LDS: 8 regions of 16KB: [slot(2)][op A/B][half(2)][128 rows][128B], dbuf 128KB.
// Rotation: MM(1,1)+MM(1,0) of tile t execute at the TOP of iteration t+1
// (register-only, 32 MFMA) covering that tile's B reads; MM(0,0) covers RD_A(1);
// aQ0 of t+1 pre-read after barrier2 (covered by next top cluster). lgkmcnt(0)
// before the stage barrier drains all slot reads (WAR-safe staging); vmcnt(8)
// counted — never 0 in steady state.
// OUT_MODE: 0=f32 plain(+bias), 1=bf16 plain, 2=bf16 perm64, 3=f32 split-K slice
template<int OUT_MODE, bool BIAS, bool RELU, bool SWZ>
__global__ __launch_bounds__(512, 2) void gemm256(
    const unsigned short* __restrict__ A, const unsigned short* __restrict__ BT,
    void* __restrict__ C, const float* __restrict__ bias,
    int K, int cstride, int nvalid, int Mt, int KC) {
  __shared__ alignas(16) char Lds[131072];
  const int tid = threadIdx.x;
  const int wave = tid >> 6, lane = tid & 63;
  const int wm = wave >> 2, wn = wave & 3;          // 2x4 wave grid
  const int g4 = lane >> 4, l15 = lane & 15, l7 = lane & 7;
  const int brow = (wn & 1) * 64;                   // B row base within its half

  int bm, bn;
  if (SWZ) {
    // one bn per XCD per round (B panel L2-resident); all bm sweep A per round
    const int xcd = blockIdx.x & 7;
    const int j = blockIdx.x >> 3;
    bm = j & 31;
    bn = (j >> 5) * 8 + xcd;
    const int Nt = (nvalid + 255) >> 8;
    if (bn >= Nt) return;                           // dead pad block
  } else {
    bm = blockIdx.x % Mt;
    bn = blockIdx.x / Mt;
  }

  const int NTt = K >> 6;
  const int kb = blockIdx.z * KC;
  const int NT = min(KC, NTt - kb);
  const unsigned short* Ag = A + (size_t)bm * 256 * K + (size_t)kb * 64;
  const unsigned short* Bg = BT + (size_t)bn * 256 * K + (size_t)kb * 64;

  const int srow = tid >> 3;        // staging row 0..63 (second gload adds 64)
  const int schk = (tid & 7) * 8;   // element offset of this thread's 16B chunk

  // stage half h of operand op (0=A,1=B) for tile t into region [t&1][op][h]
  auto stageHalf = [&](const unsigned short* G, int t, int op, int h) {
    char* base = Lds + ((((t & 1) << 2) | (op << 1) | h) << 14) + (wave << 10);
    const unsigned short* src = G + (size_t)(h * 128 + srow) * K + (size_t)t * 64 + schk;
    gload16(src, base);                         // rows 0..63 of the half
    gload16(src + (size_t)64 * K, base + 8192); // rows 64..127
  };
  auto stageTile = [&](int t) {   // 8 gloads
    stageHalf(Ag, t, 0, 0); stageHalf(Ag, t, 0, 1);
    stageHalf(Bg, t, 1, 0); stageHalf(Bg, t, 1, 1);
  };

  const char* Ab0 = Lds + (((0 << 2) | (0 << 1) | wm) << 14);
  const char* Ab1 = Lds + (((1 << 2) | (0 << 1) | wm) << 14);
  const char* Bb0 = Lds + (((0 << 2) | (1 << 1) | (wn >> 1)) << 14);
  const char* Bb1 = Lds + (((1 << 2) | (1 << 1) | (wn >> 1)) << 14);

  f32x4 acc[8][4];
#pragma unroll
  for (int i = 0; i < 8; i++)
#pragma unroll
    for (int j = 0; j < 4; j++) acc[i][j] = (f32x4){0.f, 0.f, 0.f, 0.f};

  short8 aQ0[4][2], aQ1[4][2], bL[2][2], bH[2][2];

#define RD_AQ(DST, BASE, QM) do {                                                \
  _Pragma("unroll") for (int i2 = 0; i2 < 4; ++i2)                               \
  _Pragma("unroll") for (int ks = 0; ks < 2; ++ks)                               \
    DST[i2][ks] = *(const short8*)((BASE) + ((QM) * 64 + i2 * 16 + l15) * 128    \
                                   + ((((ks << 2) | g4) ^ l7) << 4));            \
} while (0)

#define RD_BQ(DST, BASE, QN) do {                                               \
  _Pragma("unroll") for (int j2 = 0; j2 < 2; ++j2)                              \
  _Pragma("unroll") for (int ks = 0; ks < 2; ++ks)                              \
    DST[j2][ks] = *(const short8*)((BASE) + (brow + (QN) * 32 + j2 * 16 + l15) * 128 \
                                   + ((((ks << 2) | g4) ^ l7) << 4));           \
} while (0)

#define MMQ(QM, QN, ASET, BSET) do {                                            \
  __builtin_amdgcn_s_setprio(1);                                                \
  _Pragma("unroll") for (int i2 = 0; i2 < 4; ++i2)                              \
  _Pragma("unroll") for (int j2 = 0; j2 < 2; ++j2)                              \
  _Pragma("unroll") for (int ks = 0; ks < 2; ++ks)                              \
    acc[(QM) * 4 + i2][(QN) * 2 + j2] =                                         \
        mfma16(ASET[i2][ks], BSET[j2][ks], acc[(QM) * 4 + i2][(QN) * 2 + j2]);  \
  __builtin_amdgcn_s_setprio(0);                                                \
} while (0)

  // prologue: stage tiles 0,1; wait tile 0 (tile 1 in flight); pre-read tile0 Q0
  stageTile(0);
  if (NT > 1) {
    stageTile(1);
    asm volatile("s_waitcnt vmcnt(8)" ::: "memory");
  } else {
    asm volatile("s_waitcnt vmcnt(0)" ::: "memory");
  }
  asm volatile("s_barrier" ::: "memory");
  RD_AQ(aQ0, Ab0, 0);

  for (int t = 0; t < NT; ++t) {
    const char* Ac = (t & 1) ? Ab1 : Ab0;
    const char* Bc = (t & 1) ? Bb1 : Bb0;

    // rotated clusters of tile t-1 (register-only): cover this tile's B reads
    if (t > 0) {
      MMQ(1, 1, aQ1, bH);
      MMQ(1, 0, aQ1, bL);
    }
    RD_BQ(bL, Bc, 0);
    RD_BQ(bH, Bc, 1);
    MMQ(0, 0, aQ0, bL);          // bL arrives under the 32 rotated MFMAs
    RD_AQ(aQ1, Ac, 1);
    MMQ(0, 1, aQ0, bH);          // aQ1 arrives under MM(0,0)+MM(0,1)
    asm volatile("s_waitcnt lgkmcnt(0)" ::: "memory");   // drain slot reads (WAR)
    asm volatile("s_barrier" ::: "memory");              // slot t&1 reusable
    if (t + 2 < NT) {
      stageTile(t + 2);
      asm volatile("s_waitcnt vmcnt(8)" ::: "memory");   // t+1 resident (counted)
    } else if (t + 1 < NT) {
      asm volatile("s_waitcnt vmcnt(0)" ::: "memory");
    }
    if (t + 1 < NT) {
      asm volatile("s_barrier" ::: "memory");            // tile t+1 visible
      const char* An = (t & 1) ? Ab0 : Ab1;
      RD_AQ(aQ0, An, 0);        // pre-read next tile Q0 (consumed after next top)
    }
  }
  // epilogue clusters of the last tile
  MMQ(1, 1, aQ1, bH);
  MMQ(1, 0, aQ1, bL);

#undef RD_AQ
#undef RD_BQ
#undef MMQ

  // epilogue: 16x16 C/D layout col = lane&15, row = (lane>>4)*4 + tt  [m89/m91]
  const int m0 = bm * 256 + wm * 128;
  const int n0 = bn * 256 + wn * 64;
  const int rb = g4 * 4;
#pragma unroll
  for (int i = 0; i < 8; i++) {
#pragma unroll
    for (int j = 0; j < 4; j++) {
      int c = n0 + j * 16 + l15;
      if (c >= nvalid) continue;
      float bv = BIAS ? bias[c] : 0.f;
#pragma unroll
      for (int tt = 0; tt < 4; tt++) {
        int r = m0 + i * 16 + rb + tt;
        float v = acc[i][j][tt] + bv;
        if (RELU) v = fmaxf(v, 0.f);
        if (OUT_MODE == 0) {
          ((float*)C)[(size_t)r * cstride + c] = v;
        } else if (OUT_MODE == 1) {
          ((unsigned short*)C)[(size_t)r * cstride + c] = f2bf(v);
        } else if (OUT_MODE == 2) {
          int pos = (c & ~63) + perm64(c & 63, r);
          ((unsigned short*)C)[(size_t)r * cstride + pos] = f2bf(v);
        } else {
          ((float*)C)[(size_t)blockIdx.z * (Mt * 256) * cstride + (size_t)r * cstride + c] = v;
        }
      }
    }
  }
}

// ---------------- split-K finish: sum slices + bias (+relu) -> bf16 perm64 ----------
template<bool RELU>
__global__ void finish_kernel(const float* __restrict__ acc, const float* __restrict__ bias,
                              unsigned short* __restrict__ out, int S, int M, int N) {
  int idx = blockIdx.x * 256 + threadIdx.x;
  if (idx >= M * N) return;
  int r = idx / N, c = idx - r * N;
  float s = bias[c];
  for (int k = 0; k < S; k++) s += acc[(size_t)k * M * N + (size_t)r * N + c];
  if (RELU) s = fmaxf(s, 0.f);
  out[(size_t)r * N + (c & ~63) + perm64(c & 63, r)] = f2bf(s);
}

// ---------------- conversions ----------------
__global__ void conv_x_kernel(const float* __restrict__ x, unsigned short* __restrict__ out) {
  int idx = blockIdx.x * 256 + threadIdx.x;          // one per 4-elem group
  constexpr int GR = KP1 / 4;
  if (idx >= MP * GR) return;
  int row = idx / GR, k = (idx - row * GR) * 4;
  unsigned short v[4] = {0, 0, 0, 0};
  if (row < NN && k < F) {
    const float* p = x + (size_t)row * F + k;
    v[0] = f2bf(p[0]); v[1] = f2bf(p[1]); v[2] = f2bf(p[2]); v[3] = f2bf(p[3]);
  }
  int pos = (k & ~63) + perm64(k & 63, row);
  uint2 pk;
  pk.x = (unsigned)v[0] | ((unsigned)v[1] << 16);
  pk.y = (unsigned)v[2] | ((unsigned)v[3] << 16);
  *(uint2*)&out[(size_t)row * KP1 + pos] = pk;
}

// in: f32 [K][N] row-major  ->  out: bf16 [NPad][KPad] (transposed, perm64)
__global__ void convT_kernel(const float* __restrict__ in, unsigned short* __restrict__ out,
                             int K, int N, int KPad, int NPad) {
  __shared__ float tile[32][33];
  int n0 = blockIdx.x * 32, k0 = blockIdx.y * 32;
  int tx = threadIdx.x, ty = threadIdx.y;
#pragma unroll
  for (int i = 0; i < 4; i++) {
    int k = k0 + ty + i * 8, n = n0 + tx;
    tile[ty + i * 8][tx] = (k < K && n < N) ? in[(size_t)k * N + n] : 0.f;
  }
  __syncthreads();
#pragma unroll
  for (int i = 0; i < 4; i++) {
    int n = n0 + ty + i * 8, k = k0 + tx;
    if (n < NPad && k < KPad) {
      int pos = (k & ~63) + perm64(k & 63, n);
      out[(size_t)n * KPad + pos] = f2bf(tile[tx][ty + i * 8]);
    }
  }
}

// ---------------- attention logits ----------------
__global__ void logits_kernel(const unsigned short* __restrict__ xh,
                              const float* __restrict__ a_src, const float* __restrict__ a_dst,
                              float* __restrict__ al_s, float* __restrict__ al_d) {
  int wid = blockIdx.x * 4 + (threadIdx.x >> 6);
  int lane = threadIdx.x & 63;
  int n = wid / NH, h = wid - n * NH;
  if (n >= NN) return;
  const unsigned short* row = xh + (size_t)n * NP + h * F;
  const float* as = a_src + h * F;
  const float* ad = a_dst + h * F;
  float ss = 0.f, sd = 0.f;
  for (int f0 = lane; f0 < F; f0 += 64) {
    float v = bf2f(row[f0]);
    ss += v * as[f0]; sd += v * ad[f0];
  }
#pragma unroll
  for (int o = 32; o > 0; o >>= 1) { ss += __shfl_down(ss, o); sd += __shfl_down(sd, o); }
  if (lane == 0) { al_s[wid] = ss; al_d[wid] = sd; }
}

// ---------------- CSR over dst ----------------
__global__ void edge_count_kernel(const int* __restrict__ ei, int* __restrict__ deg) {
  int e = blockIdx.x * 256 + threadIdx.x;
  if (e >= ET) return;
  int d = (e < NE) ? ei[NE + e] : (e - NE);
  atomicAdd(&deg[d], 1);
}

__global__ void scan_kernel(const int* __restrict__ deg, int* __restrict__ rs,
                            int* __restrict__ cursor) {
  __shared__ int part[1024];
  int t = threadIdx.x;
  int base = t * 8, s = 0, loc[8];
#pragma unroll
  for (int i = 0; i < 8; i++) { loc[i] = s; int idx = base + i; s += (idx < NN) ? deg[idx] : 0; }
  part[t] = s;
  __syncthreads();
  for (int off = 1; off < 1024; off <<= 1) {
    int v = (t >= off) ? part[t - off] : 0;
    __syncthreads();
    part[t] += v;
    __syncthreads();
  }
  int pre = (t > 0) ? part[t - 1] : 0;
#pragma unroll
  for (int i = 0; i < 8; i++) {
    int idx = base + i;
    if (idx <= NN) { rs[idx] = pre + loc[i]; cursor[idx] = pre + loc[i]; }
  }
}

__global__ void edge_fill_kernel(const int* __restrict__ ei, int* __restrict__ cursor,
                                 int* __restrict__ eidx) {
  int e = blockIdx.x * 256 + threadIdx.x;
  if (e >= ET) return;
  int d = (e < NE) ? ei[NE + e] : (e - NE);
  int pos = atomicAdd(&cursor[d], 1);
  eidx[pos] = e;
}

__global__ void dinv_kernel(const int* __restrict__ deg, float* __restrict__ dinv) {
  int n = blockIdx.x * 256 + threadIdx.x;
  if (n < NN) dinv[n] = rsqrtf((float)max(deg[n], 1));
}

// ---------------- edge softmax ----------------
__global__ void alpha_kernel(const int* __restrict__ ei, const int* __restrict__ rs,
                             const int* __restrict__ eidx, const float* __restrict__ al_s,
                             const float* __restrict__ al_d, float* __restrict__ alpha) {
  int w = blockIdx.x * 256 + threadIdx.x;
  if (w >= NN * NH) return;
  int n = w / NH, h = w - n * NH;
  int s0 = rs[n], s1 = rs[n + 1];
  float ad = al_d[w];
  float m = -3.0e38f;
  for (int i = s0; i < s1; i++) {
    int e = eidx[i]; int s = (e < NE) ? ei[e] : (e - NE);
    float x = al_s[s * NH + h] + ad;
    x = (x > 0.f) ? x : 0.2f * x;
    m = fmaxf(m, x);
  }
  float z = 0.f;
  for (int i = s0; i < s1; i++) {
    int e = eidx[i]; int s = (e < NE) ? ei[e] : (e - NE);
    float x = al_s[s * NH + h] + ad;
    x = (x > 0.f) ? x : 0.2f * x;
    float ex = __expf(x - m);
    alpha[(size_t)i * NH + h] = ex;
    z += ex;
  }
  float inv = 1.f / (z + 1e-16f);
  for (int i = s0; i < s1; i++) alpha[(size_t)i * NH + h] *= inv;
}

DEVFN void axpy8(float al, uint4 r, float* a) {
  a[0] += al * bf2f((unsigned short)(r.x & 0xffff));
  a[1] += al * bf2f((unsigned short)(r.x >> 16));
  a[2] += al * bf2f((unsigned short)(r.y & 0xffff));
  a[3] += al * bf2f((unsigned short)(r.y >> 16));
  a[4] += al * bf2f((unsigned short)(r.z & 0xffff));
  a[5] += al * bf2f((unsigned short)(r.z >> 16));
  a[6] += al * bf2f((unsigned short)(r.w & 0xffff));
  a[7] += al * bf2f((unsigned short)(r.w >> 16));
}
DEVFN uint4 pack8(const float* a) {
  uint4 p;
  p.x = (unsigned)f2bf(a[0]) | ((unsigned)f2bf(a[1]) << 16);
  p.y = (unsigned)f2bf(a[2]) | ((unsigned)f2bf(a[3]) << 16);
  p.z = (unsigned)f2bf(a[4]) | ((unsigned)f2bf(a[5]) << 16);
  p.w = (unsigned)f2bf(a[6]) | ((unsigned)f2bf(a[7]) << 16);
  return p;
}

constexpr int MAXE = 256;   // per-block cached edges (deg mean ~5; overflow path below)

// ---------------- GAT aggregation -> h (bf16, perm64 layout) ----------------
__global__ __launch_bounds__(256) void gat_agg_kernel(
    const unsigned short* __restrict__ xh, const int* __restrict__ ei,
    const int* __restrict__ rs, const int* __restrict__ eidx,
    const float* __restrict__ alpha, const float* __restrict__ bgat,
    unsigned short* __restrict__ hbf) {
  __shared__ int   Ls[MAXE];
  __shared__ float La[MAXE][NH];
  int n = blockIdx.x, t = threadIdx.x;
  int s0 = rs[n], d = rs[n + 1] - s0;
  int dc = min(d, MAXE);
  for (int i = t; i < dc; i += 256) {
    int e = eidx[s0 + i]; Ls[i] = (e < NE) ? ei[e] : (e - NE);
  }
  for (int j = t; j < dc * NH; j += 256)
    La[j / NH][j % NH] = alpha[(size_t)(s0 + j / NH) * NH + j % NH];
  __syncthreads();
  for (int c8 = t; c8 < KP2 / 8; c8 += 256) {
    int c = c8 * 8;
    int pos = (c & ~63) + ((((c >> 3) & 7) ^ (n & 7)) << 3);  // perm64, 8 contiguous
    if (c >= HF) {
      *(uint4*)&hbf[(size_t)n * KP2 + pos] = make_uint4(0u, 0u, 0u, 0u);
      continue;
    }
    int h = c / F;                          // 680 % 8 == 0: chunk never straddles heads
    float a[8] = {0.f, 0.f, 0.f, 0.f, 0.f, 0.f, 0.f, 0.f};
    for (int i = 0; i < dc; ++i)
      axpy8(La[i][h], *(const uint4*)&xh[(size_t)Ls[i] * NP + c], a);
    for (int i = MAXE; i < d; ++i) {        // overflow path (unused for this graph)
      int e = eidx[s0 + i]; int s = (e < NE) ? ei[e] : (e - NE);
      axpy8(alpha[(size_t)(s0 + i) * NH + h], *(const uint4*)&xh[(size_t)s * NP + c], a);
    }
#pragma unroll
    for (int q = 0; q < 8; ++q) a[q] = fmaxf(a[q] + bgat[c + q], 0.f);
    *(uint4*)&hbf[(size_t)n * KP2 + pos] = pack8(a);
  }
}

// ---------------- GCN aggregation -> h2 (bf16, plain layout) ----------------
__global__ __launch_bounds__(256) void gcn_agg_kernel(
    const unsigned short* __restrict__ xw, const int* __restrict__ ei,
    const int* __restrict__ rs, const int* __restrict__ eidx,
    const float* __restrict__ dinv, const float* __restrict__ bgcn,
    unsigned short* __restrict__ h2) {
  __shared__ int   Ls[MAXE];
  __shared__ float Lw[MAXE];
  int n = blockIdx.x, t = threadIdx.x;
  int s0 = rs[n], d = rs[n + 1] - s0;
  int dc = min(d, MAXE);
  float dn = dinv[n];
  for (int i = t; i < dc; i += 256) {
    int e = eidx[s0 + i]; int s = (e < NE) ? ei[e] : (e - NE);
    Ls[i] = s; Lw[i] = dinv[s] * dn;
  }
  __syncthreads();
  for (int c8 = t; c8 < HF / 8; c8 += 256) {
    int c = c8 * 8;
    float a[8] = {0.f, 0.f, 0.f, 0.f, 0.f, 0.f, 0.f, 0.f};
    for (int i = 0; i < dc; ++i)
      axpy8(Lw[i], *(const uint4*)&xw[(size_t)Ls[i] * NP + c], a);
    for (int i = MAXE; i < d; ++i) {
      int e = eidx[s0 + i]; int s = (e < NE) ? ei[e] : (e - NE);
      axpy8(dinv[s] * dn, *(const uint4*)&xw[(size_t)s * NP + c], a);
    }
#pragma unroll
    for (int q = 0; q < 8; ++q) a[q] = fmaxf(a[q] + bgcn[c + q], 0.f);
    *(uint4*)&h2[(size_t)n * KP2 + c] = pack8(a);
  }
}

// ---------------- pooling ----------------
__global__ void pool_init_kernel(int* gstart, int* gend, int* gcnt) {
  int g = threadIdx.x;
  gstart[g] = 0x7fffffff; gend[g] = 0; gcnt[g] = 0;
}
__global__ void pool_scan_kernel(const int* __restrict__ batch, int* gstart, int* gend, int* gcnt) {
  int n = blockIdx.x * 256 + threadIdx.x;
  if (n >= NN) return;
  int b = batch[n];
  if (b >= 0 && b < NG) {
    atomicMin(&gstart[b], n);
    atomicMax(&gend[b], n + 1);
    atomicAdd(&gcnt[b], 1);
  }
}
// batch is contiguous (arange // (N/G)) -> [gstart,gend) all belong to g
__global__ void pool_kernel(const unsigned short* __restrict__ h2,
                            const int* __restrict__ gstart, const int* __restrict__ gend,
                            const int* __restrict__ gcnt, unsigned short* __restrict__ gbf) {
  int g = blockIdx.x, t = threadIdx.x;
  int s = gstart[g], e = gend[g];
  float inv = 1.f / (float)max(gcnt[g], 1);
  for (int c8 = t; c8 < HF / 8; c8 += 256) {
    int c = c8 * 8;
    float mx[8], sm[8];
#pragma unroll
    for (int q = 0; q < 8; ++q) { mx[q] = -3.0e38f; sm[q] = 0.f; }
    for (int n = s; n < e; ++n) {
      uint4 r = *(const uint4*)&h2[(size_t)n * KP2 + c];
      float v[8];
      v[0] = bf2f((unsigned short)(r.x & 0xffff)); v[1] = bf2f((unsigned short)(r.x >> 16));
      v[2] = bf2f((unsigned short)(r.y & 0xffff)); v[3] = bf2f((unsigned short)(r.y >> 16));
      v[4] = bf2f((unsigned short)(r.z & 0xffff)); v[5] = bf2f((unsigned short)(r.z >> 16));
      v[6] = bf2f((unsigned short)(r.w & 0xffff)); v[7] = bf2f((unsigned short)(r.w >> 16));
#pragma unroll
      for (int q = 0; q < 8; ++q) { mx[q] = fmaxf(mx[q], v[q]); sm[q] += v[q]; }
    }
#pragma unroll
    for (int q = 0; q < 8; ++q) sm[q] *= inv;
    int c2 = HF + c;
    int pos1 = (c & ~63) + ((((c >> 3) & 7) ^ (g & 7)) << 3);
    int pos2 = (c2 & ~63) + ((((c2 >> 3) & 7) ^ (g & 7)) << 3);
    *(uint4*)&gbf[(size_t)g * KM1P + pos1] = pack8(mx);
    *(uint4*)&gbf[(size_t)g * KM1P + pos2] = pack8(sm);
  }
}

// ---------------- launch ----------------
extern "C" void kernel_launch(void* const* d_in, const int* in_sizes, int n_in,
                              void* d_out, int out_size, void* d_ws, size_t ws_size,
                              hipStream_t stream) {
  (void)in_sizes; (void)n_in; (void)out_size; (void)ws_size;
  const float* x     = (const float*)d_in[0];
  const int*   ei    = (const int*)d_in[1];
  const int*   batch = (const int*)d_in[2];
  const float* W_gat = (const float*)d_in[3];
  const float* a_src = (const float*)d_in[4];
  const float* a_dst = (const float*)d_in[5];
  const float* b_gat = (const float*)d_in[6];
  const float* W_gcn = (const float*)d_in[7];
  const float* b_gcn = (const float*)d_in[8];
  const float* W1    = (const float*)d_in[9];
  const float* b1    = (const float*)d_in[10];
  const float* W2    = (const float*)d_in[11];
  const float* b2    = (const float*)d_in[12];
  const float* W3    = (const float*)d_in[13];
  const float* b3    = (const float*)d_in[14];
  float* out = (float*)d_out;

  char* ws = (char*)d_ws;
  size_t off = 0;
  auto alloc = [&](size_t bytes) -> void* {
    void* p = ws + off;
    off += (bytes + 255) & ~(size_t)255;
    return p;
  };
  unsigned short* bufA  = (unsigned short*)alloc((size_t)MP * NP * 2);   // xh, then xw
  unsigned short* bufB  = (unsigned short*)alloc((size_t)MP * KP2 * 2);  // h (perm), then h2 (plain)
  unsigned short* wgcnT = (unsigned short*)alloc((size_t)NP * KP2 * 2);
  unsigned short* xbf   = (unsigned short*)alloc((size_t)MP * KP1 * 2);
  unsigned short* wgatT = (unsigned short*)alloc((size_t)NP * KP1 * 2);
  unsigned short* w1T   = (unsigned short*)alloc((size_t)512 * KM1P * 2);
  unsigned short* gbf   = (unsigned short*)alloc((size_t)NG * KM1P * 2);
  unsigned short* w2T   = (unsigned short*)alloc((size_t)256 * 512 * 2);
  unsigned short* w3T   = (unsigned short*)alloc((size_t)256 * 128 * 2);
  unsigned short* g1bf  = (unsigned short*)alloc((size_t)NG * 512 * 2);
  unsigned short* g2bf  = (unsigned short*)alloc((size_t)NG * 128 * 2);
  float* accf  = (float*)alloc((size_t)32 * 256 * 512 * 4);              // split-K slices
  float* al_s  = (float*)alloc((size_t)NN * NH * 4);
  float* al_d  = (float*)alloc((size_t)NN * NH * 4);
  float* alpha = (float*)alloc((size_t)ET * NH * 4);
  float* dinv  = (float*)alloc((size_t)NN * 4);
  int* deg    = (int*)alloc((size_t)NN * 4);
  int* rs     = (int*)alloc((size_t)(NN + 1) * 4);
  int* cursor = (int*)alloc((size_t)(NN + 1) * 4);
  int* eidx   = (int*)alloc((size_t)ET * 4);
  int* gstart = (int*)alloc((size_t)NG * 4);
  int* gend   = (int*)alloc((size_t)NG * 4);
  int* gcnt   = (int*)alloc((size_t)NG * 4);

  constexpr int GRID_SWZ = 8 * 32 * 4;   // xcd(8) x bm(32) x bn-rounds(4) = 1024

  // --- stage 0: conversions / padding ---
  conv_x_kernel<<<(MP * (KP1 / 4)) / 256, 256, 0, stream>>>(x, xbf);
  convT_kernel<<<dim3(NP / 32, KP1 / 32), dim3(32, 8), 0, stream>>>(W_gat, wgatT, F, HF, KP1, NP);
  convT_kernel<<<dim3(NP / 32, KP2 / 32), dim3(32, 8), 0, stream>>>(W_gcn, wgcnT, HF, HF, KP2, NP);
  convT_kernel<<<dim3(512 / 32, KM1P / 32), dim3(32, 8), 0, stream>>>(W1, w1T, 2 * HF, 512, KM1P, 512);
  convT_kernel<<<dim3(256 / 32, 512 / 32), dim3(32, 8), 0, stream>>>(W2, w2T, 512, 128, 512, 256);
  convT_kernel<<<dim3(256 / 32, 128 / 32), dim3(32, 8), 0, stream>>>(W3, w3T, 128, 64, 128, 256);
  hipMemsetAsync(deg, 0, (size_t)NN * 4, stream);
  hipMemsetAsync((char*)bufB + (size_t)NN * KP2 * 2, 0, (size_t)(MP - NN) * KP2 * 2, stream);
  hipMemsetAsync(gbf, 0, (size_t)NG * KM1P * 2, stream);   // K-pad cols of pooled features

  // --- GEMM1: xh = x @ W_gat (bf16 out, plain layout) ---
  gemm256<1, false, false, true><<<dim3(GRID_SWZ, 1, 1), 512, 0, stream>>>(
      xbf, wgatT, bufA, nullptr, KP1, NP, NP, 32, KP1 / 64);

  // --- attention logits ---
  logits_kernel<<<(NN * NH) / 4, 256, 0, stream>>>(bufA, a_src, a_dst, al_s, al_d);

  // --- CSR build over dst ---
  edge_count_kernel<<<(ET + 255) / 256, 256, 0, stream>>>(ei, deg);
  scan_kernel<<<1, 1024, 0, stream>>>(deg, rs, cursor);
  edge_fill_kernel<<<(ET + 255) / 256, 256, 0, stream>>>(ei, cursor, eidx);
  dinv_kernel<<<(NN + 255) / 256, 256, 0, stream>>>(deg, dinv);

  // --- edge softmax ---
  alpha_kernel<<<(NN * NH + 255) / 256, 256, 0, stream>>>(ei, rs, eidx, al_s, al_d, alpha);

  // --- GAT aggregate -> h (bf16, perm64 layout) ---
  gat_agg_kernel<<<NN, 256, 0, stream>>>(bufA, ei, rs, eidx, alpha, b_gat, bufB);

  // --- GCN GEMM: xw = h @ W_gcn ---
  gemm256<1, false, false, true><<<dim3(GRID_SWZ, 1, 1), 512, 0, stream>>>(
      bufB, wgcnT, bufA, nullptr, KP2, NP, NP, 32, KP2 / 64);

  // --- GCN aggregate -> h2 (bf16, plain layout, reuses bufB) ---
  gcn_agg_kernel<<<NN, 256, 0, stream>>>(bufA, ei, rs, eidx, dinv, b_gcn, bufB);

  // --- pooling -> g (bf16, perm64 layout) ---
  pool_init_kernel<<<1, 256, 0, stream>>>(gstart, gend, gcnt);
  pool_scan_kernel<<<(NN + 255) / 256, 256, 0, stream>>>(batch, gstart, gend, gcnt);
  pool_kernel<<<NG, 256, 0, stream>>>(bufB, gstart, gend, gcnt, gbf);

  // --- MLP (split-K, f32 slices, then finish) ---
  // MLP1: 256x512 @ K=13632 (213 tiles): z=31 slices x KC=7 -> 62 blocks
  gemm256<3, false, false, false><<<dim3(2, 1, 31), 512, 0, stream>>>(
      gbf, w1T, accf, nullptr, KM1P, 512, 512, 1, 7);
  finish_kernel<true><<<(256 * 512) / 256, 256, 0, stream>>>(accf, b1, g1bf, 31, 256, 512);

  // MLP2: 256x128 @ K=512 (8 tiles): z=4 x KC=2
  gemm256<3, false, false, false><<<dim3(1, 1, 4), 512, 0, stream>>>(
      g1bf, w2T, accf, nullptr, 512, 128, 128, 1, 2);
  finish_kernel<false><<<(256 * 128) / 256, 256, 0, stream>>>(accf, b2, g2bf, 4, 256, 128);

  // MLP3: 256x64 @ K=128 (2 tiles): direct f32 out with bias
  gemm256<0, true, false, false><<<dim3(1, 1, 1), 512, 0, stream>>>(
      g2bf, w3T, out, b3, 128, 64, 64, 1, 2);
}